// Round 3
// baseline (1048.692 us; speedup 1.0000x reference)
//
#include <hip/hip_runtime.h>
#include <hip/hip_bf16.h>

#define NN 131072   // nodes
#define NG 4096     // graphs
#define N0 32       // nodes/graph
#define EPG 128     // edges/graph
#define NE 524288   // edges

typedef __hip_bfloat16 bf16;

// ---------------- GEMM: H = X @ W  (X: N x K f32, W: K x 128 f32, H: N x 128 f32)
// 64 rows/block, 256 threads, each thread 8 rows x 4 cols. In-place safe (all
// global reads of this block's X rows precede its writes; blocks own disjoint rows).
template<int K>
__global__ __launch_bounds__(256) void gemm_kernel(
    const float* __restrict__ X, const float* __restrict__ W, float* Hout)
{
    constexpr int KC = (K < 64) ? K : 64;   // chunk size (41 or 64)
    __shared__ float Ws[64 * 128];          // [kk][col]
    __shared__ float Xs[64 * KC];           // [row][kk]
    int tid = threadIdx.x;
    long row0 = (long)blockIdx.x * 64;
    int c4 = (tid & 31) * 4;                // col group
    int r0 = (tid >> 5) * 8;                // row group

    float acc[8][4];
#pragma unroll
    for (int i = 0; i < 8; i++)
#pragma unroll
        for (int j = 0; j < 4; j++) acc[i][j] = 0.f;

    for (int k0 = 0; k0 < K; k0 += KC) {
        __syncthreads();
        for (int i = tid; i < KC * 128; i += 256) Ws[i] = W[k0 * 128 + i];
        for (int i = tid; i < 64 * KC; i += 256) {
            int r = i / KC, kk = i - r * KC;
            Xs[i] = X[(row0 + r) * K + k0 + kk];
        }
        __syncthreads();
        for (int kk = 0; kk < KC; kk++) {
            float4 wv = *(const float4*)&Ws[kk * 128 + c4];
#pragma unroll
            for (int i = 0; i < 8; i++) {
                float xv = Xs[(r0 + i) * KC + kk];
                acc[i][0] += xv * wv.x; acc[i][1] += xv * wv.y;
                acc[i][2] += xv * wv.z; acc[i][3] += xv * wv.w;
            }
        }
    }
#pragma unroll
    for (int i = 0; i < 8; i++) {
        long rb = (row0 + r0 + i) * 128 + c4;
#pragma unroll
        for (int j = 0; j < 4; j++) Hout[rb + j] = acc[i][j];
    }
}

// ---------------- per-graph GAT attention + aggregation (in-place safe: tile
// staged to LDS before any global write)
__global__ __launch_bounds__(256) void attn_kernel(
    const float* Hin,
    const int* __restrict__ src, const int* __restrict__ dst,
    const float* __restrict__ edge_attr,
    const unsigned char* __restrict__ nm,
    const float* __restrict__ We,
    const float* __restrict__ as_, const float* __restrict__ ad_,
    const float* __restrict__ ae_, const float* __restrict__ bias,
    float* Hout)
{
    int g = blockIdx.x, tid = threadIdx.x;
    __shared__ float hs[4096];
    __shared__ float hsd[32][2], hdd[32][2];
    __shared__ float ve[2][10];
    __shared__ float aed[128][2], alpha[128][2], aself[32][2];
    __shared__ float lsum[32][2];
    __shared__ int   lcnt[32];
    __shared__ int   lse[128], lde[128];
    __shared__ unsigned char emk[128], nml[32];
    __shared__ float mx[32][2], den[32][2];
    __shared__ float wgt[128][2], wself[32][2];
    __shared__ int   deg[32], offs[33], curs[32], lst[128];

    long gb = (long)g * 4096;

    // phase 1: load tile, init
    for (int i = tid; i < 4096; i += 256) hs[i] = Hin[gb + i];
    if (tid < 32) {
        lcnt[tid] = 0; lsum[tid][0] = 0.f; lsum[tid][1] = 0.f;
        deg[tid] = 0; curs[tid] = 0; nml[tid] = nm[g * 32 + tid];
    }
    if (tid >= 32 && tid < 52) {   // ve[h][j] = sum_c We[j,h*64+c]*ae[h,c]
        int t = tid - 32;
        int h = t / 10, j = t - 10 * h;
        float s = 0.f;
        for (int c = 0; c < 64; c++) s += We[j * 128 + h * 64 + c] * ae_[h * 64 + c];
        ve[h][j] = s;
    }
    __syncthreads();

    // phase 2: node attention dots + edge prep
    {
        int node = tid >> 3, l8 = tid & 7;
        float s0 = 0, s1 = 0, d0 = 0, d1 = 0;
        for (int m = 0; m < 8; m++) {
            int c = l8 + 8 * m;
            float h0 = hs[node * 128 + c], h1 = hs[node * 128 + 64 + c];
            s0 += h0 * as_[c];      s1 += h1 * as_[64 + c];
            d0 += h0 * ad_[c];      d1 += h1 * ad_[64 + c];
        }
#pragma unroll
        for (int o = 4; o >= 1; o >>= 1) {
            s0 += __shfl_xor(s0, o); s1 += __shfl_xor(s1, o);
            d0 += __shfl_xor(d0, o); d1 += __shfl_xor(d1, o);
        }
        if (l8 == 0) { hsd[node][0] = s0; hsd[node][1] = s1; hdd[node][0] = d0; hdd[node][1] = d1; }
    }
    if (tid < 128) {
        int e = tid;
        int gs = src[g * 128 + e], gd = dst[g * 128 + e];
        int ls = gs & 31, ld = gd & 31;
        lse[e] = ls; lde[e] = ld;
        unsigned char m = (unsigned char)(nm[gs] & nm[gd]);
        emk[e] = m;
        float a0 = 0, a1 = 0;
        long eb = (long)(g * 128 + e) * 10;
        for (int j = 0; j < 10; j++) {
            float eav = edge_attr[eb + j];
            a0 += eav * ve[0][j]; a1 += eav * ve[1][j];
        }
        aed[e][0] = a0; aed[e][1] = a1;
        if (m) {
            atomicAdd(&lsum[ld][0], a0);
            atomicAdd(&lsum[ld][1], a1);
            atomicAdd(&lcnt[ld], 1);
        }
        atomicAdd(&deg[ld], 1);
    }
    __syncthreads();

    // phase 3: alphas (leaky-relu then mask), self-loop alphas, CSR offsets
    if (tid < 128) {
        int e = tid;
#pragma unroll
        for (int h = 0; h < 2; h++) {
            float a = hsd[lse[e]][h] + hdd[lde[e]][h] + aed[e][h];
            a = (a >= 0.f) ? a : 0.2f * a;
            alpha[e][h] = emk[e] ? a : -1e9f;
        }
    }
    if (tid >= 128 && tid < 160) {
        int n = tid - 128;
        float c = (lcnt[n] > 0) ? (float)lcnt[n] : 1.0f;
#pragma unroll
        for (int h = 0; h < 2; h++) {
            float a = hsd[n][h] + hdd[n][h] + lsum[n][h] / c;
            a = (a >= 0.f) ? a : 0.2f * a;
            aself[n][h] = nml[n] ? a : -1e9f;
        }
    }
    if (tid == 255) {
        int o = 0;
        for (int n = 0; n < 32; n++) { offs[n] = o; o += deg[n]; }
        offs[32] = o;
    }
    __syncthreads();

    // phase 4: segment max + denominator (masks handled explicitly)
    if (tid < 64) {
        int n = tid >> 1, h = tid & 1;
        float m = aself[n][h];
        for (int e = 0; e < 128; e++) if (lde[e] == n) { float a = alpha[e][h]; m = (a > m) ? a : m; }
        float s = nml[n] ? expf(aself[n][h] - m) : 0.f;
        for (int e = 0; e < 128; e++) if (lde[e] == n && emk[e]) s += expf(alpha[e][h] - m);
        mx[n][h] = m; den[n][h] = s;
    }
    __syncthreads();

    // phase 5: softmax weights + CSR fill
    if (tid < 128) {
        int e = tid;
#pragma unroll
        for (int h = 0; h < 2; h++) {
            float w = 0.f;
            if (emk[e]) w = expf(alpha[e][h] - mx[lde[e]][h]) / fmaxf(den[lde[e]][h], 1e-16f);
            wgt[e][h] = w;
        }
        int n = lde[e];
        int p = atomicAdd(&curs[n], 1);
        lst[offs[n] + p] = e;
    }
    if (tid >= 128 && tid < 160) {
        int n = tid - 128;
#pragma unroll
        for (int h = 0; h < 2; h++) {
            float w = 0.f;
            if (nml[n]) w = expf(aself[n][h] - mx[n][h]) / fmaxf(den[n][h], 1e-16f);
            wself[n][h] = w;
        }
    }
    __syncthreads();

    // phase 6: weighted aggregation + bias, write
    for (int i = 0; i < 16; i++) {
        int idx = tid + 256 * i;
        int n = idx >> 7, d = idx & 127, h = d >> 6;
        float acc = wself[n][h] * hs[n * 128 + d];
        int e1 = offs[n + 1];
        for (int j = offs[n]; j < e1; j++) {
            int e = lst[j];
            acc += wgt[e][h] * hs[lse[e] * 128 + d];
        }
        Hout[gb + idx] = acc + bias[d];
    }
}

// ---------------- BN stats: per-channel sum / sumsq over unmasked nodes
__global__ __launch_bounds__(256) void bn_stats_kernel(
    const float* __restrict__ X, const unsigned char* __restrict__ nm, float* __restrict__ sums)
{
    __shared__ float sb[256], qb[256];
    int tid = threadIdx.x;
    int d = tid & 127, half = tid >> 7;
    long start = (long)blockIdx.x * 256;
    float s = 0.f, q = 0.f;
    for (int r = half; r < 256; r += 2) {
        long row = start + r;
        if (nm[row]) {
            float v = X[row * 128 + d];
            s += v; q += v * v;
        }
    }
    sb[tid] = s; qb[tid] = q;
    __syncthreads();
    if (tid < 128) {
        atomicAdd(&sums[tid], sb[tid] + sb[tid + 128]);
        atomicAdd(&sums[128 + tid], qb[tid] + qb[tid + 128]);
    }
}

// ---------------- BN finalize: mean, rstd, normalized pool weight
__global__ __launch_bounds__(128) void bn_finalize_kernel(
    const float* __restrict__ sums, float n,
    const float* __restrict__ pw, float* __restrict__ stat)
{
    int d = threadIdx.x;  // 128
    float mean = sums[d] / n;
    float var = sums[128 + d] / n - mean * mean;
    if (var < 0.f) var = 0.f;
    float rstd = rsqrtf(var + 1e-5f);
    float p = pw[d];
    float q = p * p;
#pragma unroll
    for (int o = 32; o >= 1; o >>= 1) q += __shfl_xor(q, o);
    __shared__ float w2[2];
    if ((d & 63) == 0) w2[d >> 6] = q;
    __syncthreads();
    float nrm = sqrtf(w2[0] + w2[1]);
    stat[d] = mean; stat[128 + d] = rstd; stat[256 + d] = p / nrm;
}

// ---------------- BN apply + relu + per-graph top-k pool + graph-mean accumulate
__global__ __launch_bounds__(256) void pool_kernel(
    const float* Hin, const float* __restrict__ stat,
    const float* __restrict__ gamma, const float* __restrict__ beta,
    unsigned char* __restrict__ nm, float* Xout,
    float* __restrict__ z, int K)
{
    int g = blockIdx.x, tid = threadIdx.x;
    __shared__ float xs[4096];
    __shared__ float sc[32];
    __shared__ unsigned char nml[32], sel[32];
    long gb = (long)g * 4096;

    for (int i = tid; i < 4096; i += 256) {
        int d = i & 127;
        float v = Hin[gb + i];
        v = gamma[d] * (v - stat[d]) * stat[128 + d] + beta[d];
        xs[i] = fmaxf(v, 0.f);
    }
    if (tid < 32) nml[tid] = nm[g * 32 + tid];
    __syncthreads();

    {   // scores: sc[n] = x[n] . pw_normalized
        int node = tid >> 3, l8 = tid & 7;
        float s = 0.f;
        for (int m = 0; m < 8; m++) {
            int c = l8 + 8 * m;
            s += xs[node * 128 + c] * stat[256 + c] + xs[node * 128 + 64 + c] * stat[256 + 64 + c];
        }
#pragma unroll
        for (int o = 4; o >= 1; o >>= 1) s += __shfl_xor(s, o);
        if (l8 == 0) sc[node] = s;
    }
    __syncthreads();

    if (tid < 32) {   // stable top-k selection (ties: lower index wins), matches lax.top_k
        int n = tid;
        float sn = nml[n] ? sc[n] : -1e9f;
        int cnt = 0;
        for (int j = 0; j < 32; j++) {
            float sj = nml[j] ? sc[j] : -1e9f;
            cnt += (sj > sn || (sj == sn && j < n)) ? 1 : 0;
        }
        unsigned char sl = (cnt < K) ? 1 : 0;
        sel[n] = sl;
        nm[g * 32 + n] = sl;
    }
    __syncthreads();

    for (int i = tid; i < 4096; i += 256) {
        int n = i >> 7;
        float v = sel[n] ? xs[i] * tanhf(sc[n]) : 0.f;
        xs[i] = v;
        Xout[gb + i] = v;
    }
    __syncthreads();

    if (tid < 128) {   // graph mean over exactly K kept nodes, accumulate into z
        float s = 0.f;
        for (int n = 0; n < 32; n++) s += xs[n * 128 + tid];
        z[(long)g * 128 + tid] += s / (float)K;
    }
}

// ---------------- final MLP head: out = relu(z@fw1+fb1)@fw2+fb2
__global__ __launch_bounds__(64) void head_kernel(
    const float* __restrict__ z, const float* __restrict__ fw1, const float* __restrict__ fb1,
    const float* __restrict__ fw2, const float* __restrict__ fb2, float* __restrict__ out)
{
    int g = blockIdx.x, j = threadIdx.x;  // 64 threads
    const float* zg = z + (long)g * 128;
    float acc = fb1[j];
    for (int d = 0; d < 128; d++) acc += zg[d] * fw1[d * 64 + j];
    acc = fmaxf(acc, 0.f);
    float v = acc * fw2[j];
#pragma unroll
    for (int o = 32; o >= 1; o >>= 1) v += __shfl_xor(v, o);
    if (j == 0) out[g] = v + fb2[0];
}

extern "C" void kernel_launch(void* const* d_in, const int* in_sizes, int n_in,
                              void* d_out, int out_size, void* d_ws, size_t ws_size,
                              hipStream_t stream)
{
    const float* X0 = (const float*)d_in[0];
    const int*   EI = (const int*)d_in[1];
    const float* EA = (const float*)d_in[2];
    const int* srcp = EI;
    const int* dstp = EI + NE;

    // workspace layout (~69 MB)
    float* bufA = (float*)d_ws;                       // NN*128 f32 (in-place activations)
    float* z    = bufA + (size_t)NN * 128;            // NG*128 f32
    float* sums = z + (size_t)NG * 128;               // 256 f32
    float* stat = sums + 256;                         // 384 f32
    unsigned char* nm = (unsigned char*)(stat + 384); // NN bytes

    hipMemsetAsync(nm, 1, NN, stream);
    hipMemsetAsync(z, 0, (size_t)NG * 128 * sizeof(float), stream);

    const float ncnt[3] = { 131072.f, 4096.f * 29.f, 4096.f * 27.f };
    const int   KK[3]   = { 29, 27, 25 };

    for (int l = 0; l < 3; l++) {
        int base = 4 + 9 * l;
        const float* W   = (const float*)d_in[base + 0];
        const float* We  = (const float*)d_in[base + 1];
        const float* as_ = (const float*)d_in[base + 2];
        const float* ad_ = (const float*)d_in[base + 3];
        const float* ae_ = (const float*)d_in[base + 4];
        const float* bb  = (const float*)d_in[base + 5];
        const float* gg  = (const float*)d_in[base + 6];
        const float* be  = (const float*)d_in[base + 7];
        const float* pw  = (const float*)d_in[base + 8];

        hipMemsetAsync(sums, 0, 256 * sizeof(float), stream);
        if (l == 0) gemm_kernel<41><<<NN / 64, 256, 0, stream>>>(X0, W, bufA);
        else        gemm_kernel<128><<<NN / 64, 256, 0, stream>>>(bufA, W, bufA);
        attn_kernel<<<NG, 256, 0, stream>>>(bufA, srcp, dstp, EA, nm, We, as_, ad_, ae_, bb, bufA);
        bn_stats_kernel<<<512, 256, 0, stream>>>(bufA, nm, sums);
        bn_finalize_kernel<<<1, 128, 0, stream>>>(sums, ncnt[l], pw, stat);
        pool_kernel<<<NG, 256, 0, stream>>>(bufA, stat, gg, be, nm, bufA, z, KK[l]);
    }

    head_kernel<<<NG, 64, 0, stream>>>(z, (const float*)d_in[31], (const float*)d_in[32],
                                       (const float*)d_in[33], (const float*)d_in[34],
                                       (float*)d_out);
}

// Round 4
// 1008.602 us; speedup vs baseline: 1.0397x; 1.0397x over previous
//
#include <hip/hip_runtime.h>

#define NN 131072   // nodes
#define NG 4096     // graphs
#define NE 524288   // edges

__device__ __forceinline__ float lrelu(float a){ return a>=0.f ? a : 0.2f*a; }

// ============================================================================
// Fused per-graph layer kernel: [pool(prev)] -> GEMM -> GAT attention -> stats
// PMODE: 0 = no pool stage (layer 0, read X0 32xK)
//        1 = pool stage, previous mask = all-ones (layer 1)
//        2 = pool stage, previous mask from nmg (layer 2)
// KSEL: top-k of the pool stage. K: GEMM inner dim (41 or 128).
// ============================================================================
template<int K, int PMODE, int KSEL>
__global__ __launch_bounds__(256) void fused_kernel(
    const float* __restrict__ Xin,   // PMODE==0: X0 (N x 41)
    float* bufA,                     // activations N x 128 (read if PMODE>0, always written)
    const int* __restrict__ srcp, const int* __restrict__ dstp,
    const float* __restrict__ EA,    // E x 10
    unsigned char* nmg,              // node mask (global, persisted between layers)
    const float* __restrict__ stat,  // [0:128] mean, [128:256] rstd, [256:384] pw/||pw||, [384:404] ve
    const float* __restrict__ gamma, const float* __restrict__ beta,  // prev-layer BN affine
    const float* __restrict__ Wg,    // K x 128
    const float* __restrict__ as_, const float* __restrict__ ad_,     // H x C = 128
    const float* __restrict__ bb,    // bias 128
    float* zacc,                     // NG x 128 readout accumulator
    float* sums)                     // 256 global BN partial sums
{
    __shared__ float xs[4096], hs[4096], wsb[4096];
    __shared__ float hsd[64], hdd[64], aself[64], lsumS[64], wself[64], scS[32], tsS[32];
    __shared__ int lcnt[32], lseS[128], ldeS[128], selS[32], nmlS[32],
                   degS[32], offs[33], curs[32], lst[128];
    // overlays in wsb (free after GEMM)
    float* alpha = wsb;        // [128][2]
    float* wgt   = wsb + 256;  // [128][2]
    float* mxS   = wsb + 512;  // [32][2]
    float* denS  = wsb + 576;  // [32][2]

    int g = blockIdx.x, tid = threadIdx.x;
    long gb = (long)g * 4096;

    // ---- init small arrays
    if (tid < 64) lsumS[tid] = 0.f;
    if (tid < 32) {
        lcnt[tid] = 0; degS[tid] = 0; curs[tid] = 0;
        if (PMODE == 0) { selS[tid] = 1; nmlS[tid] = 1; }
        else if (PMODE == 1) nmlS[tid] = 1;
        else nmlS[tid] = (int)nmg[g * 32 + tid];
    }

    // ---- edge topology + edge-attr dot (kept in registers across GEMM)
    float ea0 = 0.f, ea1 = 0.f;
    int myls = 0, myld = 0;
    if (tid < 128) {
        myls = srcp[g * 128 + tid] & 31;
        myld = dstp[g * 128 + tid] & 31;
        lseS[tid] = myls; ldeS[tid] = myld;
        const float* ep = EA + (long)(g * 128 + tid) * 10;
#pragma unroll
        for (int j = 0; j < 10; j++) {
            float v = ep[j];
            ea0 += v * stat[384 + j];
            ea1 += v * stat[394 + j];
        }
    }

    // ---- input stage: raw load or BN+relu
    if (PMODE == 0) {
        for (int i = tid; i < 32 * K; i += 256) xs[i] = Xin[(long)g * (32 * K) + i];
    } else {
        for (int i = tid; i < 1024; i += 256) {
            float4 v = *(const float4*)&bufA[gb + i * 4];
            int d0 = (i * 4) & 127;
            v.x = fmaxf(gamma[d0    ] * (v.x - stat[d0    ]) * stat[128 + d0    ] + beta[d0    ], 0.f);
            v.y = fmaxf(gamma[d0 + 1] * (v.y - stat[d0 + 1]) * stat[128 + d0 + 1] + beta[d0 + 1], 0.f);
            v.z = fmaxf(gamma[d0 + 2] * (v.z - stat[d0 + 2]) * stat[128 + d0 + 2] + beta[d0 + 2], 0.f);
            v.w = fmaxf(gamma[d0 + 3] * (v.w - stat[d0 + 3]) * stat[128 + d0 + 3] + beta[d0 + 3], 0.f);
            *(float4*)&xs[i * 4] = v;
        }
    }
    __syncthreads();   // S1

    // ---- degree atomics + pool scores
    if (tid < 128) atomicAdd(&degS[myld], 1);
    if (PMODE > 0) {
        int node = tid >> 3, l8 = tid & 7;
        float s = 0.f;
        for (int m = 0; m < 16; m++) { int c = l8 + 8 * m; s += xs[node * 128 + c] * stat[256 + c]; }
        s += __shfl_xor(s, 4); s += __shfl_xor(s, 2); s += __shfl_xor(s, 1);
        if (l8 == 0) scS[node] = s;
    }
    __syncthreads();   // S2

    // ---- stable top-k (ties: lower index), CSR offsets
    if (PMODE > 0 && tid < 32) {
        float sn = nmlS[tid] ? scS[tid] : -1e9f;
        int cnt = 0;
        for (int j2 = 0; j2 < 32; j2++) {
            float sj = nmlS[j2] ? scS[j2] : -1e9f;
            cnt += (sj > sn || (sj == sn && j2 < tid)) ? 1 : 0;
        }
        int sl = (cnt < KSEL) ? 1 : 0;
        selS[tid] = sl;
        nmg[g * 32 + tid] = (unsigned char)sl;
        tsS[tid] = sl ? tanhf(scS[tid]) : 0.f;
    }
    if (tid == 255) {
        int o = 0;
        for (int n = 0; n < 32; n++) { offs[n] = o; o += degS[n]; }
        offs[32] = o;
    }
    __syncthreads();   // S3

    // ---- gate + loop-attr sums + CSR fill
    if (PMODE > 0) {
        for (int i = tid; i < 4096; i += 256) xs[i] *= tsS[i >> 7];
    }
    if (tid < 128) {
        if (selS[myls] & selS[myld]) {
            atomicAdd(&lsumS[myld * 2], ea0);
            atomicAdd(&lsumS[myld * 2 + 1], ea1);
            atomicAdd(&lcnt[myld], 1);
        }
        int p = atomicAdd(&curs[myld], 1);
        lst[offs[myld] + p] = tid;
    }
    __syncthreads();   // S4

    // ---- readout accumulation (z += graph_mean of gated x)
    if (PMODE > 0 && tid < 128) {
        float s = 0.f;
        for (int n = 0; n < 32; n++) s += xs[n * 128 + tid];
        zacc[(long)g * 128 + tid] += s * (1.0f / (float)KSEL);
    }

    // ---- GEMM: H(32x128) = xs(32xK) @ Wg(Kx128), W staged in 32-row chunks
    int r4 = (tid >> 5) * 4, c4 = (tid & 31) * 4;
    float acc[4][4];
#pragma unroll
    for (int i = 0; i < 4; i++)
#pragma unroll
        for (int j = 0; j < 4; j++) acc[i][j] = 0.f;

    for (int k0 = 0; k0 < K; k0 += 32) {
        const int CH = (K - k0 < 32) ? (K - k0) : 32;
        for (int i = tid; i < CH * 128; i += 256) wsb[i] = Wg[k0 * 128 + i];
        __syncthreads();
        if (K == 128) {
#pragma unroll
            for (int kk4 = 0; kk4 < 8; kk4++) {
                float4 xv[4], wv[4];
#pragma unroll
                for (int i = 0; i < 4; i++) xv[i] = *(const float4*)&xs[(r4 + i) * 128 + k0 + kk4 * 4];
#pragma unroll
                for (int j = 0; j < 4; j++) wv[j] = *(const float4*)&wsb[(kk4 * 4 + j) * 128 + c4];
#pragma unroll
                for (int i = 0; i < 4; i++) {
                    acc[i][0] += xv[i].x * wv[0].x + xv[i].y * wv[1].x + xv[i].z * wv[2].x + xv[i].w * wv[3].x;
                    acc[i][1] += xv[i].x * wv[0].y + xv[i].y * wv[1].y + xv[i].z * wv[2].y + xv[i].w * wv[3].y;
                    acc[i][2] += xv[i].x * wv[0].z + xv[i].y * wv[1].z + xv[i].z * wv[2].z + xv[i].w * wv[3].z;
                    acc[i][3] += xv[i].x * wv[0].w + xv[i].y * wv[1].w + xv[i].z * wv[2].w + xv[i].w * wv[3].w;
                }
            }
        } else {
            for (int kk = 0; kk < CH; kk++) {
                float4 wv = *(const float4*)&wsb[kk * 128 + c4];
#pragma unroll
                for (int i = 0; i < 4; i++) {
                    float xv = xs[(r4 + i) * K + k0 + kk];
                    acc[i][0] += xv * wv.x; acc[i][1] += xv * wv.y;
                    acc[i][2] += xv * wv.z; acc[i][3] += xv * wv.w;
                }
            }
        }
        __syncthreads();
    }
#pragma unroll
    for (int i = 0; i < 4; i++)
        *(float4*)&hs[(r4 + i) * 128 + c4] = make_float4(acc[i][0], acc[i][1], acc[i][2], acc[i][3]);
    __syncthreads();   // hs ready, wsb free

    // ---- attention: node dots
    {
        int node = tid >> 3, l8 = tid & 7;
        float s0 = 0, s1 = 0, d0 = 0, d1 = 0;
        for (int m = 0; m < 8; m++) {
            int c = l8 + 8 * m;
            float h0 = hs[node * 128 + c], h1 = hs[node * 128 + 64 + c];
            s0 += h0 * as_[c];      s1 += h1 * as_[64 + c];
            d0 += h0 * ad_[c];      d1 += h1 * ad_[64 + c];
        }
        s0 += __shfl_xor(s0, 4); s0 += __shfl_xor(s0, 2); s0 += __shfl_xor(s0, 1);
        s1 += __shfl_xor(s1, 4); s1 += __shfl_xor(s1, 2); s1 += __shfl_xor(s1, 1);
        d0 += __shfl_xor(d0, 4); d0 += __shfl_xor(d0, 2); d0 += __shfl_xor(d0, 1);
        d1 += __shfl_xor(d1, 4); d1 += __shfl_xor(d1, 2); d1 += __shfl_xor(d1, 1);
        if (l8 == 0) { hsd[node * 2] = s0; hsd[node * 2 + 1] = s1; hdd[node * 2] = d0; hdd[node * 2 + 1] = d1; }
    }
    __syncthreads();

    // ---- alphas (edge + self-loop)
    if (tid < 128) {
        int mk = selS[myls] & selS[myld];
        float a0 = hsd[myls * 2] + hdd[myld * 2] + ea0;
        float a1 = hsd[myls * 2 + 1] + hdd[myld * 2 + 1] + ea1;
        alpha[tid * 2]     = mk ? lrelu(a0) : -1e9f;
        alpha[tid * 2 + 1] = mk ? lrelu(a1) : -1e9f;
    } else if (tid < 160) {
        int n = tid - 128;
        float c = (lcnt[n] > 0) ? (float)lcnt[n] : 1.f;
        float a0 = hsd[n * 2] + hdd[n * 2] + lsumS[n * 2] / c;
        float a1 = hsd[n * 2 + 1] + hdd[n * 2 + 1] + lsumS[n * 2 + 1] / c;
        aself[n * 2]     = selS[n] ? lrelu(a0) : -1e9f;
        aself[n * 2 + 1] = selS[n] ? lrelu(a1) : -1e9f;
    }
    __syncthreads();

    // ---- segment max + denominator via CSR (only deg(n) iterations)
    if (tid < 64) {
        int n = tid >> 1, h = tid & 1;
        float av = aself[n * 2 + h];
        float m = av;
        int j0 = offs[n], j1 = offs[n + 1];
        for (int j = j0; j < j1; j++) { float a = alpha[lst[j] * 2 + h]; m = (a > m) ? a : m; }
        float s = (av > -1e8f) ? __expf(av - m) : 0.f;
        for (int j = j0; j < j1; j++) { float a = alpha[lst[j] * 2 + h]; if (a > -1e8f) s += __expf(a - m); }
        mxS[n * 2 + h] = m; denS[n * 2 + h] = s;
    }
    __syncthreads();

    // ---- softmax weights
    if (tid < 128) {
#pragma unroll
        for (int h = 0; h < 2; h++) {
            float a = alpha[tid * 2 + h];
            wgt[tid * 2 + h] = (a > -1e8f)
                ? __expf(a - mxS[myld * 2 + h]) / fmaxf(denS[myld * 2 + h], 1e-16f) : 0.f;
        }
    } else if (tid < 160) {
        int n = tid - 128;
#pragma unroll
        for (int h = 0; h < 2; h++) {
            float a = aself[n * 2 + h];
            wself[n * 2 + h] = (a > -1e8f)
                ? __expf(a - mxS[n * 2 + h]) / fmaxf(denS[n * 2 + h], 1e-16f) : 0.f;
        }
    }
    __syncthreads();

    // ---- weighted aggregation + bias -> xs
    for (int i = 0; i < 16; i++) {
        int idx = tid + 256 * i;
        int n = idx >> 7, d = idx & 127, h = d >> 6;
        float a = wself[n * 2 + h] * hs[n * 128 + d];
        int j1 = offs[n + 1];
        for (int j = offs[n]; j < j1; j++) {
            int e = lst[j];
            a += wgt[e * 2 + h] * hs[lseS[e] * 128 + d];
        }
        xs[idx] = a + bb[d];
    }
    __syncthreads();

    // ---- masked BN stats (atomics) + store tile
    if (tid < 128) {
        float s = 0.f, q = 0.f;
        for (int n = 0; n < 32; n++) if (selS[n]) { float v = xs[n * 128 + tid]; s += v; q += v * v; }
        atomicAdd(&sums[tid], s);
        atomicAdd(&sums[128 + tid], q);
    }
    for (int i = tid; i < 1024; i += 256)
        *(float4*)&bufA[gb + i * 4] = *(const float4*)&xs[i * 4];
}

// ============================================================================
// setup: zero sums, compute ve (= We . ae per head) for layer 0
// ============================================================================
__global__ __launch_bounds__(128) void setup_kernel(
    float* sums, float* stat, const float* __restrict__ We, const float* __restrict__ ae)
{
    int t = threadIdx.x;
    sums[t] = 0.f; sums[128 + t] = 0.f;
    if (t < 20) {
        int h = t / 10, j = t - 10 * h;
        float s = 0.f;
        for (int c = 0; c < 64; c++) s += We[j * 128 + h * 64 + c] * ae[h * 64 + c];
        stat[384 + t] = s;
    }
}

// ============================================================================
// finalize: BN mean/rstd, normalized pool weight, next layer's ve, re-zero sums
// ============================================================================
__global__ __launch_bounds__(128) void finalize_kernel(
    float* sums, float n, const float* __restrict__ pw, float* stat,
    const float* __restrict__ Wen, const float* __restrict__ aen)
{
    int d = threadIdx.x;
    float s0 = sums[d], s1 = sums[128 + d];
    float mean = s0 / n;
    float var = s1 / n - mean * mean;
    if (var < 0.f) var = 0.f;
    float rstd = rsqrtf(var + 1e-5f);
    float p = pw[d];
    float q = p * p;
#pragma unroll
    for (int o = 32; o >= 1; o >>= 1) q += __shfl_xor(q, o);
    __shared__ float w2[2];
    if ((d & 63) == 0) w2[d >> 6] = q;
    __syncthreads();
    float nrm = sqrtf(w2[0] + w2[1]);
    stat[d] = mean; stat[128 + d] = rstd; stat[256 + d] = p / nrm;
    if (d < 20) {
        int h = d / 10, j = d - 10 * h;
        float s = 0.f;
        for (int c = 0; c < 64; c++) s += Wen[j * 128 + h * 64 + c] * aen[h * 64 + c];
        stat[384 + d] = s;
    }
    sums[d] = 0.f; sums[128 + d] = 0.f;
}

// ============================================================================
// final: pool layer-2 + readout + MLP head
// ============================================================================
__global__ __launch_bounds__(256) void final_kernel(
    const float* __restrict__ bufA, const unsigned char* __restrict__ nmg,
    const float* __restrict__ stat,
    const float* __restrict__ gamma, const float* __restrict__ beta,
    const float* __restrict__ zacc,
    const float* __restrict__ fw1, const float* __restrict__ fb1,
    const float* __restrict__ fw2, const float* __restrict__ fb2,
    float* __restrict__ out)
{
    __shared__ float xs[4096], zt[128], hred[64], scS[32], tsS[32];
    __shared__ int nmlS[32];
    int g = blockIdx.x, tid = threadIdx.x;
    long gb = (long)g * 4096;

    if (tid < 32) nmlS[tid] = (int)nmg[g * 32 + tid];
    for (int i = tid; i < 1024; i += 256) {
        float4 v = *(const float4*)&bufA[gb + i * 4];
        int d0 = (i * 4) & 127;
        v.x = fmaxf(gamma[d0    ] * (v.x - stat[d0    ]) * stat[128 + d0    ] + beta[d0    ], 0.f);
        v.y = fmaxf(gamma[d0 + 1] * (v.y - stat[d0 + 1]) * stat[128 + d0 + 1] + beta[d0 + 1], 0.f);
        v.z = fmaxf(gamma[d0 + 2] * (v.z - stat[d0 + 2]) * stat[128 + d0 + 2] + beta[d0 + 2], 0.f);
        v.w = fmaxf(gamma[d0 + 3] * (v.w - stat[d0 + 3]) * stat[128 + d0 + 3] + beta[d0 + 3], 0.f);
        *(float4*)&xs[i * 4] = v;
    }
    __syncthreads();

    {
        int node = tid >> 3, l8 = tid & 7;
        float s = 0.f;
        for (int m = 0; m < 16; m++) { int c = l8 + 8 * m; s += xs[node * 128 + c] * stat[256 + c]; }
        s += __shfl_xor(s, 4); s += __shfl_xor(s, 2); s += __shfl_xor(s, 1);
        if (l8 == 0) scS[node] = s;
    }
    __syncthreads();

    if (tid < 32) {
        float sn = nmlS[tid] ? scS[tid] : -1e9f;
        int cnt = 0;
        for (int j2 = 0; j2 < 32; j2++) {
            float sj = nmlS[j2] ? scS[j2] : -1e9f;
            cnt += (sj > sn || (sj == sn && j2 < tid)) ? 1 : 0;
        }
        tsS[tid] = (cnt < 25) ? tanhf(scS[tid]) : 0.f;
    }
    __syncthreads();

    if (tid < 128) {
        float s = 0.f;
        for (int n = 0; n < 32; n++) s += xs[n * 128 + tid] * tsS[n];
        zt[tid] = zacc[(long)g * 128 + tid] + s * (1.0f / 25.0f);
    }
    __syncthreads();

    // head: relu(z@fw1+fb1)@fw2+fb2
    {
        int j = tid >> 2, p = tid & 3;
        float s = 0.f;
        for (int d = p * 32; d < p * 32 + 32; d++) s += zt[d] * fw1[d * 64 + j];
        s += __shfl_xor(s, 1); s += __shfl_xor(s, 2);
        if (p == 0) hred[j] = fmaxf(s + fb1[j], 0.f) * fw2[j];
    }
    __syncthreads();
    if (tid < 64) {
        float v = hred[tid];
#pragma unroll
        for (int o = 32; o >= 1; o >>= 1) v += __shfl_xor(v, o);
        if (tid == 0) out[g] = v + fb2[0];
    }
}

extern "C" void kernel_launch(void* const* d_in, const int* in_sizes, int n_in,
                              void* d_out, int out_size, void* d_ws, size_t ws_size,
                              hipStream_t stream)
{
    const float* X0 = (const float*)d_in[0];
    const int*   EI = (const int*)d_in[1];
    const float* EA = (const float*)d_in[2];
    const int* srcp = EI;
    const int* dstp = EI + NE;

    // per-layer params: base = 4 + 9*l : W, We, as, ad, ae, b, g, be, pw
    const float* W1  = (const float*)d_in[4];  const float* We1 = (const float*)d_in[5];
    const float* as1 = (const float*)d_in[6];  const float* ad1 = (const float*)d_in[7];
    const float* ae1 = (const float*)d_in[8];  const float* b1  = (const float*)d_in[9];
    const float* g1  = (const float*)d_in[10]; const float* be1 = (const float*)d_in[11];
    const float* pw1 = (const float*)d_in[12];
    const float* W2  = (const float*)d_in[13]; const float* We2 = (const float*)d_in[14];
    const float* as2 = (const float*)d_in[15]; const float* ad2 = (const float*)d_in[16];
    const float* ae2 = (const float*)d_in[17]; const float* b2  = (const float*)d_in[18];
    const float* g2  = (const float*)d_in[19]; const float* be2 = (const float*)d_in[20];
    const float* pw2 = (const float*)d_in[21];
    const float* W3  = (const float*)d_in[22]; const float* We3 = (const float*)d_in[23];
    const float* as3 = (const float*)d_in[24]; const float* ad3 = (const float*)d_in[25];
    const float* ae3 = (const float*)d_in[26]; const float* b3  = (const float*)d_in[27];
    const float* g3  = (const float*)d_in[28]; const float* be3 = (const float*)d_in[29];
    const float* pw3 = (const float*)d_in[30];
    const float* fw1 = (const float*)d_in[31]; const float* fb1 = (const float*)d_in[32];
    const float* fw2 = (const float*)d_in[33]; const float* fb2 = (const float*)d_in[34];

    // workspace: bufA 67MB, z 2MB, sums 256f, stat 512f, nmg 128KB
    float* bufA = (float*)d_ws;
    float* z    = bufA + (size_t)NN * 128;
    float* sums = z + (size_t)NG * 128;
    float* stat = sums + 256;
    unsigned char* nmg = (unsigned char*)(stat + 512);

    hipMemsetAsync(z, 0, (size_t)NG * 128 * sizeof(float), stream);
    setup_kernel<<<1, 128, 0, stream>>>(sums, stat, We1, ae1);

    // layer 0
    fused_kernel<41, 0, 1><<<NG, 256, 0, stream>>>(
        X0, bufA, srcp, dstp, EA, nmg, stat, stat, stat, W1, as1, ad1, b1, z, sums);
    finalize_kernel<<<1, 128, 0, stream>>>(sums, 131072.f, pw1, stat, We2, ae2);

    // layer 1 (pool of layer 0: K=29, prev mask = all ones)
    fused_kernel<128, 1, 29><<<NG, 256, 0, stream>>>(
        X0, bufA, srcp, dstp, EA, nmg, stat, g1, be1, W2, as2, ad2, b2, z, sums);
    finalize_kernel<<<1, 128, 0, stream>>>(sums, 4096.f * 29.f, pw2, stat, We3, ae3);

    // layer 2 (pool of layer 1: K=27, prev mask from nmg)
    fused_kernel<128, 2, 27><<<NG, 256, 0, stream>>>(
        X0, bufA, srcp, dstp, EA, nmg, stat, g2, be2, W3, as3, ad3, b3, z, sums);
    finalize_kernel<<<1, 128, 0, stream>>>(sums, 4096.f * 27.f, pw3, stat, We3, ae3);

    // final: pool layer 2 (K=25) + readout + head
    final_kernel<<<NG, 256, 0, stream>>>(
        bufA, nmg, stat, g3, be3, z, fw1, fb1, fw2, fb2, (float*)d_out);
}

// Round 5
// 903.913 us; speedup vs baseline: 1.1602x; 1.1158x over previous
//
#include <hip/hip_runtime.h>

#define NN 131072   // nodes
#define NG 4096     // graphs
#define NE 524288   // edges

__device__ __forceinline__ float lrelu(float a){ return a>=0.f ? a : 0.2f*a; }

// ============================================================================
// pool_gemm: [pool(prev layer)] -> H = X @ W   (2 graphs = 64 rows per block)
// PMODE 0: layer 0, read X0 (64 x 41), no pool. 1: pool, prev mask all-ones.
// 2: pool, prev mask from nmg.  Writes H in-place to bufA rows.
// ============================================================================
template<int K, int PMODE, int KSEL>
__global__ __launch_bounds__(256) void pool_gemm_kernel(
    const float* __restrict__ Xin, float* bufA, unsigned char* nmg,
    const float* __restrict__ stat,    // [0:128] mean, [128:256] rstd, [256:384] pw/||pw||
    const float* __restrict__ gamma, const float* __restrict__ beta,
    const float* __restrict__ Wg,      // K x 128
    float* zacc)
{
    constexpr int XP = (K == 41) ? 44 : 132;   // padded LDS pitch
    __shared__ float xs[64 * XP];
    __shared__ float Ws[32 * 128];
    __shared__ float scS[64], tsS[64];
    __shared__ int   selS[64], nmlS[64];

    int tid = threadIdx.x;
    long row0 = (long)blockIdx.x * 64;
    int g0 = blockIdx.x * 2;

    // ---- stage input (+ BN/relu for PMODE>0)
    if (PMODE == 0) {
        for (int i = tid; i < 64 * 41; i += 256) {
            int r = i / 41, c = i - r * 41;
            xs[r * 44 + c] = Xin[row0 * 41 + i];
        }
    } else {
        for (int i = tid; i < 2048; i += 256) {
            int r = i >> 5, dc = (i & 31) * 4;
            float4 v = *(const float4*)&bufA[(row0 + r) * 128 + dc];
            v.x = fmaxf(gamma[dc    ] * (v.x - stat[dc    ]) * stat[128 + dc    ] + beta[dc    ], 0.f);
            v.y = fmaxf(gamma[dc + 1] * (v.y - stat[dc + 1]) * stat[128 + dc + 1] + beta[dc + 1], 0.f);
            v.z = fmaxf(gamma[dc + 2] * (v.z - stat[dc + 2]) * stat[128 + dc + 2] + beta[dc + 2], 0.f);
            v.w = fmaxf(gamma[dc + 3] * (v.w - stat[dc + 3]) * stat[128 + dc + 3] + beta[dc + 3], 0.f);
            *(float4*)&xs[r * XP + dc] = v;
        }
        if (tid < 64) nmlS[tid] = (PMODE == 1) ? 1 : (int)nmg[g0 * 32 + tid];
    }
    __syncthreads();

    if (PMODE > 0) {
        // ---- pool scores: node = tid>>2, 4 lanes each
        {
            int node = tid >> 2, l4 = tid & 3;
            float s = 0.f;
            for (int m = 0; m < 32; m++) { int c = l4 + 4 * m; s += xs[node * XP + c] * stat[256 + c]; }
            s += __shfl_xor(s, 2); s += __shfl_xor(s, 1);
            if (l4 == 0) scS[node] = s;
        }
        __syncthreads();
        // ---- stable top-k per graph (ties: lower index wins)
        if (tid < 64) {
            int gp = tid >> 5, n = tid & 31;
            float sn = nmlS[tid] ? scS[tid] : -1e9f;
            int cnt = 0;
            for (int j = 0; j < 32; j++) {
                float sj = nmlS[gp * 32 + j] ? scS[gp * 32 + j] : -1e9f;
                cnt += (sj > sn || (sj == sn && j < n)) ? 1 : 0;
            }
            int sl = (cnt < KSEL) ? 1 : 0;
            selS[tid] = sl;
            nmg[g0 * 32 + tid] = (unsigned char)sl;
            tsS[tid] = sl ? tanhf(scS[tid]) : 0.f;
        }
        __syncthreads();
        // ---- gate
        for (int i = tid; i < 2048; i += 256) {
            int r = i >> 5, dc = (i & 31) * 4;
            float t = tsS[r];
            float4 v = *(const float4*)&xs[r * XP + dc];
            v.x *= t; v.y *= t; v.z *= t; v.w *= t;
            *(float4*)&xs[r * XP + dc] = v;
        }
        __syncthreads();
        // ---- readout accumulation (no atomics: block owns its 2 graphs)
        {
            int gp = tid >> 7, d = tid & 127;
            float s = 0.f;
            for (int n = 0; n < 32; n++) s += xs[(gp * 32 + n) * XP + d];
            long zi = (long)(g0 + gp) * 128 + d;
            zacc[zi] += s * (1.0f / (float)KSEL);
        }
    }

    // ---- GEMM: bufA[64x128] = xs[64xK] @ Wg[Kx128]
    int r0 = (tid >> 5) * 8, c4 = (tid & 31) * 4;
    float acc[8][4];
#pragma unroll
    for (int i = 0; i < 8; i++)
#pragma unroll
        for (int j = 0; j < 4; j++) acc[i][j] = 0.f;

    for (int k0 = 0; k0 < K; k0 += 32) {
        int CH = (K - k0 < 32) ? (K - k0) : 32;
        __syncthreads();
        for (int i = tid; i < CH * 128; i += 256) Ws[i] = Wg[k0 * 128 + i];
        __syncthreads();
        if (CH == 32) {
#pragma unroll
            for (int kk4 = 0; kk4 < 8; kk4++) {
                float4 wv[4];
#pragma unroll
                for (int j = 0; j < 4; j++) wv[j] = *(const float4*)&Ws[(kk4 * 4 + j) * 128 + c4];
#pragma unroll
                for (int i = 0; i < 8; i++) {
                    float4 xv = *(const float4*)&xs[(r0 + i) * XP + k0 + kk4 * 4];
                    acc[i][0] += xv.x * wv[0].x + xv.y * wv[1].x + xv.z * wv[2].x + xv.w * wv[3].x;
                    acc[i][1] += xv.x * wv[0].y + xv.y * wv[1].y + xv.z * wv[2].y + xv.w * wv[3].y;
                    acc[i][2] += xv.x * wv[0].z + xv.y * wv[1].z + xv.z * wv[2].z + xv.w * wv[3].z;
                    acc[i][3] += xv.x * wv[0].w + xv.y * wv[1].w + xv.z * wv[2].w + xv.w * wv[3].w;
                }
            }
        } else {
            for (int kk = 0; kk < CH; kk++) {
                float4 wv = *(const float4*)&Ws[kk * 128 + c4];
#pragma unroll
                for (int i = 0; i < 8; i++) {
                    float xv = xs[(r0 + i) * XP + k0 + kk];
                    acc[i][0] += xv * wv.x; acc[i][1] += xv * wv.y;
                    acc[i][2] += xv * wv.z; acc[i][3] += xv * wv.w;
                }
            }
        }
    }
#pragma unroll
    for (int i = 0; i < 8; i++)
        *(float4*)&bufA[(row0 + r0 + i) * 128 + c4] =
            make_float4(acc[i][0], acc[i][1], acc[i][2], acc[i][3]);
}

// ============================================================================
// attn: per-graph GAT via dense 32x32 attention matrix + fused BN stats
// ============================================================================
__global__ __launch_bounds__(256) void attn_kernel(
    float* bufA,
    const int* __restrict__ srcp, const int* __restrict__ dstp,
    const float* __restrict__ EA,
    const unsigned char* __restrict__ nmg,
    const float* __restrict__ stat,      // ve at [384:404]
    const float* __restrict__ as_, const float* __restrict__ ad_,
    const float* __restrict__ bb,
    float* sums)
{
    __shared__ float hs[32 * 132];
    __shared__ float Wm[2 * 32 * 33];    // [h][src][dst], padded
    __shared__ float alpha[256];         // [e][h]
    __shared__ float hsd[64], hdd[64], aself[64], mxS[64], denS[64], lsumS[64];
    __shared__ float red[512];
    __shared__ int   lseS[128], ldeS[128], lcntS[32], nmlS[32];

    int g = blockIdx.x, tid = threadIdx.x;
    long gb = (long)g * 4096;

    for (int i = tid; i < 1024; i += 256) {
        int r = i >> 5, dc = (i & 31) * 4;
        *(float4*)&hs[r * 132 + dc] = *(const float4*)&bufA[gb + i * 4];
    }
    for (int i = tid; i < 2112; i += 256) Wm[i] = 0.f;
    if (tid < 64) lsumS[tid] = 0.f;
    if (tid < 32) { lcntS[tid] = 0; nmlS[tid] = (int)nmg[g * 32 + tid]; }

    float ea0 = 0.f, ea1 = 0.f;
    int myls = 0, myld = 0, mymk = 0;
    if (tid < 128) {
        myls = srcp[g * 128 + tid] & 31;
        myld = dstp[g * 128 + tid] & 31;
        lseS[tid] = myls; ldeS[tid] = myld;
        const float* ep = EA + (long)(g * 128 + tid) * 10;
#pragma unroll
        for (int j = 0; j < 10; j++) { float v = ep[j]; ea0 += v * stat[384 + j]; ea1 += v * stat[394 + j]; }
    }
    __syncthreads();   // B1

    {   // node dots
        int node = tid >> 3, l8 = tid & 7;
        float s0 = 0, s1 = 0, d0 = 0, d1 = 0;
        for (int m = 0; m < 8; m++) {
            int c = l8 + 8 * m;
            float h0 = hs[node * 132 + c], h1 = hs[node * 132 + 64 + c];
            s0 += h0 * as_[c]; s1 += h1 * as_[64 + c];
            d0 += h0 * ad_[c]; d1 += h1 * ad_[64 + c];
        }
        s0 += __shfl_xor(s0, 4); s0 += __shfl_xor(s0, 2); s0 += __shfl_xor(s0, 1);
        s1 += __shfl_xor(s1, 4); s1 += __shfl_xor(s1, 2); s1 += __shfl_xor(s1, 1);
        d0 += __shfl_xor(d0, 4); d0 += __shfl_xor(d0, 2); d0 += __shfl_xor(d0, 1);
        d1 += __shfl_xor(d1, 4); d1 += __shfl_xor(d1, 2); d1 += __shfl_xor(d1, 1);
        if (l8 == 0) { hsd[node * 2] = s0; hsd[node * 2 + 1] = s1; hdd[node * 2] = d0; hdd[node * 2 + 1] = d1; }
    }
    if (tid < 128) {
        mymk = nmlS[myls] & nmlS[myld];
        if (mymk) {
            atomicAdd(&lsumS[myld * 2], ea0);
            atomicAdd(&lsumS[myld * 2 + 1], ea1);
            atomicAdd(&lcntS[myld], 1);
        }
    }
    __syncthreads();   // B2

    if (tid < 128) {
        float a0 = hsd[myls * 2] + hdd[myld * 2] + ea0;
        float a1 = hsd[myls * 2 + 1] + hdd[myld * 2 + 1] + ea1;
        alpha[tid * 2]     = mymk ? lrelu(a0) : -1e9f;
        alpha[tid * 2 + 1] = mymk ? lrelu(a1) : -1e9f;
    } else if (tid < 160) {
        int n = tid - 128;
        float c = (lcntS[n] > 0) ? (float)lcntS[n] : 1.f;
        float a0 = hsd[n * 2] + hdd[n * 2] + lsumS[n * 2] / c;
        float a1 = hsd[n * 2 + 1] + hdd[n * 2 + 1] + lsumS[n * 2 + 1] / c;
        aself[n * 2]     = nmlS[n] ? lrelu(a0) : -1e9f;
        aself[n * 2 + 1] = nmlS[n] ? lrelu(a1) : -1e9f;
    }
    __syncthreads();   // B3

    // segment max + denominator: 128 threads = (n, h, half)
    if (tid < 128) {
        int n = tid >> 2, h = (tid >> 1) & 1, hf = tid & 1;
        float av = aself[n * 2 + h];
        float m = av;
        for (int e = hf * 64; e < hf * 64 + 64; e++)
            if (ldeS[e] == n) m = fmaxf(m, alpha[e * 2 + h]);
        m = fmaxf(m, __shfl_xor(m, 1));
        float s = (hf == 0 && av > -1e8f) ? __expf(av - m) : 0.f;
        for (int e = hf * 64; e < hf * 64 + 64; e++)
            if (ldeS[e] == n) { float a = alpha[e * 2 + h]; if (a > -1e8f) s += __expf(a - m); }
        s += __shfl_xor(s, 1);
        if (hf == 0) { mxS[n * 2 + h] = m; denS[n * 2 + h] = fmaxf(s, 1e-16f); }
    }
    __syncthreads();   // B4

    // softmax weights -> dense Wm
    if (tid < 128) {
        if (mymk) {
            float w0 = __expf(alpha[tid * 2]     - mxS[myld * 2])     / denS[myld * 2];
            float w1 = __expf(alpha[tid * 2 + 1] - mxS[myld * 2 + 1]) / denS[myld * 2 + 1];
            atomicAdd(&Wm[myls * 33 + myld], w0);
            atomicAdd(&Wm[1056 + myls * 33 + myld], w1);
        }
    } else if (tid < 160) {
        int n = tid - 128;
        if (nmlS[n]) {
            float w0 = __expf(aself[n * 2]     - mxS[n * 2])     / denS[n * 2];
            float w1 = __expf(aself[n * 2 + 1] - mxS[n * 2 + 1]) / denS[n * 2 + 1];
            atomicAdd(&Wm[n * 33 + n], w0);
            atomicAdd(&Wm[1056 + n * 33 + n], w1);
        }
    }
    __syncthreads();   // B5

    // dense aggregation (regular 32-step loop) + bias + BN partials + writeback
    {
        int d = tid & 127, h = d >> 6, nb = tid >> 7;   // thread covers n = nb+2i
        const float* Wh = &Wm[h * 1056];
        float av[16];
#pragma unroll
        for (int i = 0; i < 16; i++) av[i] = 0.f;
        for (int s = 0; s < 32; s++) {
            float hv = hs[s * 132 + d];
            const float* wr = &Wh[s * 33 + nb];
#pragma unroll
            for (int i = 0; i < 16; i++) av[i] += wr[2 * i] * hv;
        }
        float bv = bb[d];
        float sp = 0.f, sq = 0.f;
#pragma unroll
        for (int i = 0; i < 16; i++) {
            int n = nb + 2 * i;
            float v = av[i] + bv;
            bufA[gb + n * 128 + d] = v;
            if (nmlS[n]) { sp += v; sq += v * v; }
        }
        red[tid] = sp; red[256 + tid] = sq;
    }
    __syncthreads();
    if (tid < 128) {
        atomicAdd(&sums[tid], red[tid] + red[tid + 128]);
        atomicAdd(&sums[128 + tid], red[256 + tid] + red[256 + tid + 128]);
    }
}

// ============================================================================
__global__ __launch_bounds__(128) void setup_kernel(
    float* sums, float* stat, const float* __restrict__ We, const float* __restrict__ ae)
{
    int t = threadIdx.x;
    sums[t] = 0.f; sums[128 + t] = 0.f;
    if (t < 20) {
        int h = t / 10, j = t - 10 * h;
        float s = 0.f;
        for (int c = 0; c < 64; c++) s += We[j * 128 + h * 64 + c] * ae[h * 64 + c];
        stat[384 + t] = s;
    }
}

__global__ __launch_bounds__(128) void finalize_kernel(
    float* sums, float n, const float* __restrict__ pw, float* stat,
    const float* __restrict__ Wen, const float* __restrict__ aen)
{
    int d = threadIdx.x;
    float mean = sums[d] / n;
    float var = sums[128 + d] / n - mean * mean;
    if (var < 0.f) var = 0.f;
    float rstd = rsqrtf(var + 1e-5f);
    float p = pw[d];
    float q = p * p;
#pragma unroll
    for (int o = 32; o >= 1; o >>= 1) q += __shfl_xor(q, o);
    __shared__ float w2[2];
    if ((d & 63) == 0) w2[d >> 6] = q;
    __syncthreads();
    float nrm = sqrtf(w2[0] + w2[1]);
    stat[d] = mean; stat[128 + d] = rstd; stat[256 + d] = p / nrm;
    if (d < 20) {
        int h = d / 10, j = d - 10 * h;
        float s = 0.f;
        for (int c = 0; c < 64; c++) s += Wen[j * 128 + h * 64 + c] * aen[h * 64 + c];
        stat[384 + d] = s;
    }
    sums[d] = 0.f; sums[128 + d] = 0.f;
}

// ============================================================================
// final: pool layer-2 output (K=25) + readout + MLP head
// ============================================================================
__global__ __launch_bounds__(256) void final_kernel(
    const float* __restrict__ bufA, const unsigned char* __restrict__ nmg,
    const float* __restrict__ stat,
    const float* __restrict__ gamma, const float* __restrict__ beta,
    const float* __restrict__ zacc,
    const float* __restrict__ fw1, const float* __restrict__ fb1,
    const float* __restrict__ fw2, const float* __restrict__ fb2,
    float* __restrict__ out)
{
    __shared__ float xs[32 * 132], zt[128], hred[64], scS[32], tsS[32];
    __shared__ int nmlS[32];
    int g = blockIdx.x, tid = threadIdx.x;
    long gb = (long)g * 4096;

    if (tid < 32) nmlS[tid] = (int)nmg[g * 32 + tid];
    for (int i = tid; i < 1024; i += 256) {
        int r = i >> 5, dc = (i & 31) * 4;
        float4 v = *(const float4*)&bufA[gb + i * 4];
        v.x = fmaxf(gamma[dc    ] * (v.x - stat[dc    ]) * stat[128 + dc    ] + beta[dc    ], 0.f);
        v.y = fmaxf(gamma[dc + 1] * (v.y - stat[dc + 1]) * stat[128 + dc + 1] + beta[dc + 1], 0.f);
        v.z = fmaxf(gamma[dc + 2] * (v.z - stat[dc + 2]) * stat[128 + dc + 2] + beta[dc + 2], 0.f);
        v.w = fmaxf(gamma[dc + 3] * (v.w - stat[dc + 3]) * stat[128 + dc + 3] + beta[dc + 3], 0.f);
        *(float4*)&xs[r * 132 + dc] = v;
    }
    __syncthreads();

    {
        int node = tid >> 3, l8 = tid & 7;
        float s = 0.f;
        for (int m = 0; m < 16; m++) { int c = l8 + 8 * m; s += xs[node * 132 + c] * stat[256 + c]; }
        s += __shfl_xor(s, 4); s += __shfl_xor(s, 2); s += __shfl_xor(s, 1);
        if (l8 == 0) scS[node] = s;
    }
    __syncthreads();

    if (tid < 32) {
        float sn = nmlS[tid] ? scS[tid] : -1e9f;
        int cnt = 0;
        for (int j = 0; j < 32; j++) {
            float sj = nmlS[j] ? scS[j] : -1e9f;
            cnt += (sj > sn || (sj == sn && j < tid)) ? 1 : 0;
        }
        tsS[tid] = (cnt < 25) ? tanhf(scS[tid]) : 0.f;
    }
    __syncthreads();

    if (tid < 128) {
        float s = 0.f;
        for (int n = 0; n < 32; n++) s += xs[n * 132 + tid] * tsS[n];
        zt[tid] = zacc[(long)g * 128 + tid] + s * (1.0f / 25.0f);
    }
    __syncthreads();

    {
        int j = tid >> 2, p = tid & 3;
        float s = 0.f;
        for (int d = p * 32; d < p * 32 + 32; d++) s += zt[d] * fw1[d * 64 + j];
        s += __shfl_xor(s, 1); s += __shfl_xor(s, 2);
        if (p == 0) hred[j] = fmaxf(s + fb1[j], 0.f) * fw2[j];
    }
    __syncthreads();
    if (tid < 64) {
        float v = hred[tid];
#pragma unroll
        for (int o = 32; o >= 1; o >>= 1) v += __shfl_xor(v, o);
        if (tid == 0) out[g] = v + fb2[0];
    }
}

extern "C" void kernel_launch(void* const* d_in, const int* in_sizes, int n_in,
                              void* d_out, int out_size, void* d_ws, size_t ws_size,
                              hipStream_t stream)
{
    const float* X0 = (const float*)d_in[0];
    const int*   EI = (const int*)d_in[1];
    const float* EA = (const float*)d_in[2];
    const int* srcp = EI;
    const int* dstp = EI + NE;

    const float* W1  = (const float*)d_in[4];  const float* We1 = (const float*)d_in[5];
    const float* as1 = (const float*)d_in[6];  const float* ad1 = (const float*)d_in[7];
    const float* ae1 = (const float*)d_in[8];  const float* b1  = (const float*)d_in[9];
    const float* g1  = (const float*)d_in[10]; const float* be1 = (const float*)d_in[11];
    const float* pw1 = (const float*)d_in[12];
    const float* W2  = (const float*)d_in[13]; const float* We2 = (const float*)d_in[14];
    const float* as2 = (const float*)d_in[15]; const float* ad2 = (const float*)d_in[16];
    const float* ae2 = (const float*)d_in[17]; const float* b2  = (const float*)d_in[18];
    const float* g2  = (const float*)d_in[19]; const float* be2 = (const float*)d_in[20];
    const float* pw2 = (const float*)d_in[21];
    const float* W3  = (const float*)d_in[22]; const float* We3 = (const float*)d_in[23];
    const float* as3 = (const float*)d_in[24]; const float* ad3 = (const float*)d_in[25];
    const float* ae3 = (const float*)d_in[26]; const float* b3  = (const float*)d_in[27];
    const float* g3  = (const float*)d_in[28]; const float* be3 = (const float*)d_in[29];
    const float* pw3 = (const float*)d_in[30];
    const float* fw1 = (const float*)d_in[31]; const float* fb1 = (const float*)d_in[32];
    const float* fw2 = (const float*)d_in[33]; const float* fb2 = (const float*)d_in[34];

    float* bufA = (float*)d_ws;                       // NN*128 f32
    float* z    = bufA + (size_t)NN * 128;            // NG*128 f32
    float* sums = z + (size_t)NG * 128;               // 256 f32
    float* stat = sums + 256;                         // 512 f32
    unsigned char* nmg = (unsigned char*)(stat + 512);// NN bytes (only NG*32 used)

    hipMemsetAsync(nmg, 1, NN, stream);
    hipMemsetAsync(z, 0, (size_t)NG * 128 * sizeof(float), stream);
    setup_kernel<<<1, 128, 0, stream>>>(sums, stat, We1, ae1);

    // layer 0
    pool_gemm_kernel<41, 0, 1><<<NN / 64, 256, 0, stream>>>(
        X0, bufA, nmg, stat, g1, be1, W1, z);
    attn_kernel<<<NG, 256, 0, stream>>>(bufA, srcp, dstp, EA, nmg, stat, as1, ad1, b1, sums);
    finalize_kernel<<<1, 128, 0, stream>>>(sums, 131072.f, pw1, stat, We2, ae2);

    // layer 1 (pools layer-0 output, K=29)
    pool_gemm_kernel<128, 1, 29><<<NN / 64, 256, 0, stream>>>(
        X0, bufA, nmg, stat, g1, be1, W2, z);
    attn_kernel<<<NG, 256, 0, stream>>>(bufA, srcp, dstp, EA, nmg, stat, as2, ad2, b2, sums);
    finalize_kernel<<<1, 128, 0, stream>>>(sums, 4096.f * 29.f, pw2, stat, We3, ae3);

    // layer 2 (pools layer-1 output, K=27)
    pool_gemm_kernel<128, 2, 27><<<NN / 64, 256, 0, stream>>>(
        X0, bufA, nmg, stat, g2, be2, W3, z);
    attn_kernel<<<NG, 256, 0, stream>>>(bufA, srcp, dstp, EA, nmg, stat, as3, ad3, b3, sums);
    finalize_kernel<<<1, 128, 0, stream>>>(sums, 4096.f * 27.f, pw3, stat, We3, ae3);

    // final: pool layer-2 output (K=25) + readout + head
    final_kernel<<<NG, 256, 0, stream>>>(
        bufA, nmg, stat, g3, be3, z, fw1, fb1, fw2, fb2, (float*)d_out);
}